// Round 1
// baseline (581.023 us; speedup 1.0000x reference)
//
#include <hip/hip_runtime.h>

typedef unsigned short ushort;
typedef __attribute__((ext_vector_type(8))) short short8;
typedef __attribute__((ext_vector_type(4))) float f32x4;

#define NH 16
#define DH 128
#define SEQ 2048
#define DMODEL 2048
#define GK 2048   // K dim for both GEMMs

__device__ __forceinline__ ushort f2bf(float f) {
  union { float f; unsigned u; } v; v.f = f;
  unsigned u = v.u;
  unsigned r = (u + 0x7fffu + ((u >> 16) & 1u)) >> 16;
  return (ushort)r;
}
__device__ __forceinline__ float bf2f(ushort h) {
  union { unsigned u; float f; } v; v.u = ((unsigned)h) << 16; return v.f;
}

__device__ __forceinline__ void async16(const ushort* g, ushort* l) {
  __builtin_amdgcn_global_load_lds(
      (const __attribute__((address_space(1))) unsigned*)g,
      (__attribute__((address_space(3))) unsigned*)l, 16, 0, 0);
}

// ---------------- cast fp32 -> bf16, 4 elems/thread ----------------
__global__ void cast_kernel(const float* __restrict__ src, ushort* __restrict__ dst, int n4) {
  int i = blockIdx.x * blockDim.x + threadIdx.x;
  if (i >= n4) return;
  float4 v = ((const float4*)src)[i];
  unsigned long long p = (unsigned long long)f2bf(v.x)
                       | ((unsigned long long)f2bf(v.y) << 16)
                       | ((unsigned long long)f2bf(v.z) << 32)
                       | ((unsigned long long)f2bf(v.w) << 48);
  ((unsigned long long*)dst)[i] = p;
}

// ---------------- GEMM: C[M,N] = A[M,K] * B[N,K]^T (bf16 MFMA) ----------------
// MODE 0: scatter to q/k/v head-major bf16.  MODE 1: write fp32 to out.
template<int MODE>
__global__ __launch_bounds__(256, 2)
void gemm_bt(const ushort* __restrict__ A, const ushort* __restrict__ B, int N,
             ushort* __restrict__ oq, ushort* __restrict__ ok, ushort* __restrict__ ov,
             float* __restrict__ of) {
  __shared__ ushort As[128 * 64];
  __shared__ ushort Bs[128 * 64];
  const int tid = threadIdx.x;
  const int lane = tid & 63;
  const int w = tid >> 6;
  const int wr = w >> 1, wc = w & 1;
  const int g = lane >> 4, l16 = lane & 15;
  const int m0 = blockIdx.y * 128;
  const int n0 = blockIdx.x * 128;

  f32x4 acc[4][4];
#pragma unroll
  for (int i = 0; i < 4; ++i)
#pragma unroll
    for (int j = 0; j < 4; ++j) acc[i][j] = (f32x4)0.f;

  const ushort* Ablk = A + (size_t)m0 * GK;
  const ushort* Bblk = B + (size_t)n0 * GK;

  for (int k0 = 0; k0 < GK; k0 += 64) {
#pragma unroll
    for (int it = 0; it < 4; ++it) {
      int e = (it * 256 + tid) * 8;          // element idx in 128x64 tile
      int row = e >> 6, col = e & 63;
      async16(Ablk + (size_t)row * GK + k0 + col, &As[e]);
      async16(Bblk + (size_t)row * GK + k0 + col, &Bs[e]);
    }
    __syncthreads();
#pragma unroll
    for (int ks = 0; ks < 2; ++ks) {
      short8 af[4], bf[4];
#pragma unroll
      for (int mf = 0; mf < 4; ++mf)
        af[mf] = *(const short8*)&As[(wr * 64 + mf * 16 + l16) * 64 + ks * 32 + g * 8];
#pragma unroll
      for (int nf = 0; nf < 4; ++nf)
        bf[nf] = *(const short8*)&Bs[(wc * 64 + nf * 16 + l16) * 64 + ks * 32 + g * 8];
#pragma unroll
      for (int mf = 0; mf < 4; ++mf)
#pragma unroll
        for (int nf = 0; nf < 4; ++nf)
          acc[mf][nf] = __builtin_amdgcn_mfma_f32_16x16x32_bf16(af[mf], bf[nf], acc[mf][nf], 0, 0, 0);
    }
    __syncthreads();
  }

#pragma unroll
  for (int mf = 0; mf < 4; ++mf)
#pragma unroll
    for (int nf = 0; nf < 4; ++nf)
#pragma unroll
      for (int i = 0; i < 4; ++i) {
        int row = m0 + wr * 64 + mf * 16 + g * 4 + i;
        int col = n0 + wc * 64 + nf * 16 + l16;
        float val = acc[mf][nf][i];
        if (MODE == 0) {
          int which = col >> 11;
          int r = col & 2047;
          int h = r >> 7, dh = r & 127;
          int b = row >> 11, s = row & 2047;
          size_t dst = ((size_t)(b * NH + h) * SEQ + s) * DH + dh;
          ushort* o = (which == 0) ? oq : (which == 1 ? ok : ov);
          o[dst] = f2bf(val);
        } else {
          of[(size_t)row * N + col] = val;
        }
      }
}

// ---------------- RoPE (in-place on head-major bf16 q,k) ----------------
__global__ void rope_kernel(ushort* __restrict__ q, ushort* __restrict__ k,
                            const int* __restrict__ spp) {
  int id = blockIdx.x * blockDim.x + threadIdx.x;   // < B*H*S*64
  int j = id & 63;
  int s = (id >> 6) & (SEQ - 1);
  int bh = id >> 17;
  size_t base = ((size_t)bh * SEQ + s) * DH;
  float pos = (float)(s + spp[0]);
  float ang = pos * __expf(-(float)j * (9.210340371976184f / 64.f)); // 1/10000^(j/64)
  float c = cosf(ang), sn = sinf(ang);
  float q1 = bf2f(q[base + j]), q2 = bf2f(q[base + 64 + j]);
  q[base + j]      = f2bf(q1 * c - q2 * sn);
  q[base + 64 + j] = f2bf(q2 * c + q1 * sn);
  float k1 = bf2f(k[base + j]), k2 = bf2f(k[base + 64 + j]);
  k[base + j]      = f2bf(k1 * c - k2 * sn);
  k[base + 64 + j] = f2bf(k2 * c + k1 * sn);
}

// ---------------- causal flash attention ----------------
// grid: (S/64, H, B), 256 threads (4 waves); wave w owns q rows [q0+16w, q0+16w+16)
__global__ __launch_bounds__(256, 2)
void attn_kernel(const ushort* __restrict__ Q, const ushort* __restrict__ K,
                 const ushort* __restrict__ V, ushort* __restrict__ O) {
  __shared__ ushort Ks[32 * 128];
  __shared__ ushort Vt[128 * 32];
  __shared__ ushort Ps[4][16 * 32];
  const int tid = threadIdx.x;
  const int lane = tid & 63;
  const int w = tid >> 6;
  const int g = lane >> 4, l16 = lane & 15;
  const int q0 = blockIdx.x * 64;
  const int h = blockIdx.y, b = blockIdx.z;
  const int bh = b * NH + h;
  const ushort* Qb = Q + (size_t)bh * SEQ * DH;
  const ushort* Kb = K + (size_t)bh * SEQ * DH;
  const ushort* Vb = V + (size_t)bh * SEQ * DH;

  short8 qf[4];
  {
    const ushort* qrow = Qb + (size_t)(q0 + w * 16 + l16) * DH;
#pragma unroll
    for (int ks = 0; ks < 4; ++ks) qf[ks] = *(const short8*)(qrow + ks * 32 + g * 8);
  }
  f32x4 oacc[8];
#pragma unroll
  for (int i = 0; i < 8; ++i) oacc[i] = (f32x4)0.f;
  float m_i[4], l_i[4];
#pragma unroll
  for (int i = 0; i < 4; ++i) { m_i[i] = -INFINITY; l_i[i] = 0.f; }
  const float scale = 0.08838834764831845f;  // 1/sqrt(128)

  const int nkt = q0 / 32 + 2;
  for (int kt = 0; kt < nkt; ++kt) {
    const int k0 = kt * 32;
    // stage K rows [k0,k0+32) row-major
#pragma unroll
    for (int it = 0; it < 2; ++it) {
      int e = (it * 256 + tid) * 8;
      async16(Kb + (size_t)k0 * DH + e, &Ks[e]);
    }
    // stage V transposed: Vt[dh][key]
    {
      int kk = tid >> 3;
      int d0 = (tid & 7) * 16;
      const ushort* vsrc = Vb + (size_t)(k0 + kk) * DH + d0;
      short8 t2[2];
      t2[0] = *(const short8*)vsrc;
      t2[1] = *(const short8*)(vsrc + 8);
      const ushort* tmp = (const ushort*)t2;
#pragma unroll
      for (int j = 0; j < 16; ++j) Vt[(d0 + j) * 32 + kk] = tmp[j];
    }
    __syncthreads();

    // QK^T : S[16 q][32 keys] per wave
    f32x4 sacc[2];
    sacc[0] = (f32x4)0.f; sacc[1] = (f32x4)0.f;
#pragma unroll
    for (int nf = 0; nf < 2; ++nf)
#pragma unroll
      for (int ks = 0; ks < 4; ++ks) {
        short8 kf = *(const short8*)&Ks[(nf * 16 + l16) * 128 + ks * 32 + g * 8];
        sacc[nf] = __builtin_amdgcn_mfma_f32_16x16x32_bf16(qf[ks], kf, sacc[nf], 0, 0, 0);
      }

    // online softmax
#pragma unroll
    for (int i = 0; i < 4; ++i) {
      int qrow = q0 + w * 16 + g * 4 + i;
      float pv0 = sacc[0][i] * scale;
      float pv1 = sacc[1][i] * scale;
      if (k0 + 0  * 16 + l16 > qrow) pv0 = -INFINITY;
      if (k0 + 16 + l16 > qrow) pv1 = -INFINITY;
      float mx = fmaxf(pv0, pv1);
#pragma unroll
      for (int d = 1; d < 16; d <<= 1) mx = fmaxf(mx, __shfl_xor(mx, d, 64));
      float mnew = fmaxf(m_i[i], mx);
      float alpha = __expf(m_i[i] - mnew);
      float p0 = __expf(pv0 - mnew);
      float p1 = __expf(pv1 - mnew);
      float sum = p0 + p1;
#pragma unroll
      for (int d = 1; d < 16; d <<= 1) sum += __shfl_xor(sum, d, 64);
      l_i[i] = l_i[i] * alpha + sum;
      m_i[i] = mnew;
#pragma unroll
      for (int nf2 = 0; nf2 < 8; ++nf2) oacc[nf2][i] *= alpha;
      Ps[w][(g * 4 + i) * 32 + l16]      = f2bf(p0);
      Ps[w][(g * 4 + i) * 32 + 16 + l16] = f2bf(p1);
    }
    __asm__ volatile("s_waitcnt lgkmcnt(0)" ::: "memory");

    // PV: O[16 q][128 dh] += P[16][32] @ V[32][128]
    short8 pa = *(const short8*)&Ps[w][l16 * 32 + g * 8];
#pragma unroll
    for (int nf2 = 0; nf2 < 8; ++nf2) {
      short8 vf = *(const short8*)&Vt[(nf2 * 16 + l16) * 32 + g * 8];
      oacc[nf2] = __builtin_amdgcn_mfma_f32_16x16x32_bf16(pa, vf, oacc[nf2], 0, 0, 0);
    }
    __syncthreads();
  }

#pragma unroll
  for (int i = 0; i < 4; ++i) {
    float inv = 1.f / l_i[i];
    int row = q0 + w * 16 + g * 4 + i;
    size_t obase = ((size_t)b * SEQ + row) * DMODEL + h * DH;
#pragma unroll
    for (int nf2 = 0; nf2 < 8; ++nf2)
      O[obase + nf2 * 16 + l16] = f2bf(oacc[nf2][i] * inv);
  }
}

// ---------------- launch ----------------
extern "C" void kernel_launch(void* const* d_in, const int* in_sizes, int n_in,
                              void* d_out, int out_size, void* d_ws, size_t ws_size,
                              hipStream_t stream) {
  const float* x    = (const float*)d_in[0];
  const float* wqkv = (const float*)d_in[1];
  const float* wout = (const float*)d_in[2];
  const int*   spp  = (const int*)d_in[3];
  float* out = (float*)d_out;

  ushort* ws = (ushort*)d_ws;
  ushort* xb  = ws;                       // 8,388,608
  ushort* wqb = xb + 8388608;             // 12,582,912
  ushort* wob = wqb + 12582912;           // 4,194,304
  ushort* q   = wob + 4194304;            // 8,388,608
  ushort* k   = q + 8388608;
  ushort* v   = k + 8388608;
  ushort* ao  = v + 8388608;              // 8,388,608

  cast_kernel<<<8388608 / 1024, 256, 0, stream>>>(x, xb, 8388608 / 4);
  cast_kernel<<<12582912 / 1024, 256, 0, stream>>>(wqkv, wqb, 12582912 / 4);
  cast_kernel<<<4194304 / 1024, 256, 0, stream>>>(wout, wob, 4194304 / 4);

  gemm_bt<0><<<dim3(6144 / 128, 4096 / 128), 256, 0, stream>>>(xb, wqb, 6144, q, k, v, nullptr);

  rope_kernel<<<4194304 / 256, 256, 0, stream>>>(q, k, spp);

  attn_kernel<<<dim3(SEQ / 64, NH, 2), 256, 0, stream>>>(q, k, v, ao);

  gemm_bt<1><<<dim3(2048 / 128, 4096 / 128), 256, 0, stream>>>(ao, wob, 2048, nullptr, nullptr, nullptr, out);
}

// Round 4
// 423.165 us; speedup vs baseline: 1.3730x; 1.3730x over previous
//
#include <hip/hip_runtime.h>

typedef unsigned short ushort;
typedef __attribute__((ext_vector_type(8))) short short8;
typedef __attribute__((ext_vector_type(4))) float f32x4;

#define NH 16
#define DH 128
#define SEQ 2048
#define DMODEL 2048
#define GK 2048   // K dim for both GEMMs

__device__ __forceinline__ ushort f2bf(float f) {
  union { float f; unsigned u; } v; v.f = f;
  unsigned u = v.u;
  unsigned r = (u + 0x7fffu + ((u >> 16) & 1u)) >> 16;
  return (ushort)r;
}
__device__ __forceinline__ float bf2f(ushort h) {
  union { unsigned u; float f; } v; v.u = ((unsigned)h) << 16; return v.f;
}

__device__ __forceinline__ void async16(const ushort* g, ushort* l) {
  __builtin_amdgcn_global_load_lds(
      (const __attribute__((address_space(1))) unsigned*)g,
      (__attribute__((address_space(3))) unsigned*)l, 16, 0, 0);
}

// ---------------- cast fp32 -> bf16, 4 elems/thread ----------------
__global__ void cast_kernel(const float* __restrict__ src, ushort* __restrict__ dst, int n4) {
  int i = blockIdx.x * blockDim.x + threadIdx.x;
  if (i >= n4) return;
  float4 v = ((const float4*)src)[i];
  unsigned long long p = (unsigned long long)f2bf(v.x)
                       | ((unsigned long long)f2bf(v.y) << 16)
                       | ((unsigned long long)f2bf(v.z) << 32)
                       | ((unsigned long long)f2bf(v.w) << 48);
  ((unsigned long long*)dst)[i] = p;
}

// ---------------- GEMM: C[M,N] = A[M,K] * B[N,K]^T (bf16 MFMA) ----------------
template<int MODE>
__global__ __launch_bounds__(256, 2)
void gemm_bt(const ushort* __restrict__ A, const ushort* __restrict__ B, int N,
             ushort* __restrict__ oq, ushort* __restrict__ ok, ushort* __restrict__ ov,
             float* __restrict__ of) {
  __shared__ ushort As[128 * 64];
  __shared__ ushort Bs[128 * 64];
  const int tid = threadIdx.x;
  const int lane = tid & 63;
  const int w = tid >> 6;
  const int wr = w >> 1, wc = w & 1;
  const int g = lane >> 4, l16 = lane & 15;
  const int m0 = blockIdx.y * 128;
  const int n0 = blockIdx.x * 128;

  f32x4 acc[4][4];
#pragma unroll
  for (int i = 0; i < 4; ++i)
#pragma unroll
    for (int j = 0; j < 4; ++j) acc[i][j] = (f32x4)0.f;

  const ushort* Ablk = A + (size_t)m0 * GK;
  const ushort* Bblk = B + (size_t)n0 * GK;

  for (int k0 = 0; k0 < GK; k0 += 64) {
#pragma unroll
    for (int it = 0; it < 4; ++it) {
      int e = (it * 256 + tid) * 8;          // element idx in 128x64 tile
      int row = e >> 6, col = e & 63;
      async16(Ablk + (size_t)row * GK + k0 + col, &As[e]);
      async16(Bblk + (size_t)row * GK + k0 + col, &Bs[e]);
    }
    __syncthreads();
#pragma unroll
    for (int ks = 0; ks < 2; ++ks) {
      short8 af[4], bf[4];
#pragma unroll
      for (int mf = 0; mf < 4; ++mf)
        af[mf] = *(const short8*)&As[(wr * 64 + mf * 16 + l16) * 64 + ks * 32 + g * 8];
#pragma unroll
      for (int nf = 0; nf < 4; ++nf)
        bf[nf] = *(const short8*)&Bs[(wc * 64 + nf * 16 + l16) * 64 + ks * 32 + g * 8];
#pragma unroll
      for (int mf = 0; mf < 4; ++mf)
#pragma unroll
        for (int nf = 0; nf < 4; ++nf)
          acc[mf][nf] = __builtin_amdgcn_mfma_f32_16x16x32_bf16(af[mf], bf[nf], acc[mf][nf], 0, 0, 0);
    }
    __syncthreads();
  }

#pragma unroll
  for (int mf = 0; mf < 4; ++mf)
#pragma unroll
    for (int nf = 0; nf < 4; ++nf)
#pragma unroll
      for (int i = 0; i < 4; ++i) {
        int row = m0 + wr * 64 + mf * 16 + g * 4 + i;
        int col = n0 + wc * 64 + nf * 16 + l16;
        float val = acc[mf][nf][i];
        if (MODE == 0) {
          int which = col >> 11;
          int r = col & 2047;
          int h = r >> 7, dh = r & 127;
          int b = row >> 11, s = row & 2047;
          size_t dst = ((size_t)(b * NH + h) * SEQ + s) * DH + dh;
          ushort* o = (which == 0) ? oq : (which == 1 ? ok : ov);
          o[dst] = f2bf(val);
        } else {
          of[(size_t)row * N + col] = val;
        }
      }
}

// ---------------- RoPE (in-place on head-major bf16 q,k) ----------------
__global__ void rope_kernel(ushort* __restrict__ q, ushort* __restrict__ k,
                            const int* __restrict__ spp) {
  int id = blockIdx.x * blockDim.x + threadIdx.x;   // < B*H*S*64
  int j = id & 63;
  int s = (id >> 6) & (SEQ - 1);
  int bh = id >> 17;
  size_t base = ((size_t)bh * SEQ + s) * DH;
  float pos = (float)(s + spp[0]);
  float ang = pos * __expf(-(float)j * (9.210340371976184f / 64.f)); // 1/10000^(j/64)
  float c = cosf(ang), sn = sinf(ang);
  float q1 = bf2f(q[base + j]), q2 = bf2f(q[base + 64 + j]);
  q[base + j]      = f2bf(q1 * c - q2 * sn);
  q[base + 64 + j] = f2bf(q2 * c + q1 * sn);
  float k1 = bf2f(k[base + j]), k2 = bf2f(k[base + 64 + j]);
  k[base + j]      = f2bf(k1 * c - k2 * sn);
  k[base + 64 + j] = f2bf(k2 * c + k1 * sn);
}

// ---------------- causal flash attention ----------------
// grid: (S/64, H, B), 256 threads (4 waves); wave w owns q rows [q0+16w, +16)
// KBLK=64.  K staged XOR-swizzled (pre-swizzled global source, rule 21).
// V staged TRANSPOSED (Vt[dh][kv], stride 72) via regs + scalar ds_write.
__global__ __launch_bounds__(256, 3)
void attn_kernel(const ushort* __restrict__ Q, const ushort* __restrict__ K,
                 const ushort* __restrict__ V, ushort* __restrict__ O) {
  __shared__ ushort Ks[64 * 128];        // swizzled rows, 16 KB
  __shared__ ushort Vt[128 * 72];        // V^T, row stride 72 (18 KB)
  __shared__ ushort Ps[4 * 16 * 72];     // per-wave P[16][64], row stride 72
  const int tid = threadIdx.x;
  const int lane = tid & 63;
  const int w = tid >> 6;
  const int g = lane >> 4, l16 = lane & 15;
  const int q0 = blockIdx.x * 64;
  const int h = blockIdx.y, b = blockIdx.z;
  const int bh = b * NH + h;
  const ushort* Qb = Q + (size_t)bh * SEQ * DH;
  const ushort* Kb = K + (size_t)bh * SEQ * DH;
  const ushort* Vb = V + (size_t)bh * SEQ * DH;

  short8 qf[4];
  {
    const ushort* qrow = Qb + (size_t)(q0 + w * 16 + l16) * DH;
#pragma unroll
    for (int ks = 0; ks < 4; ++ks) qf[ks] = *(const short8*)(qrow + ks * 32 + g * 8);
  }
  f32x4 oacc[8];
#pragma unroll
  for (int i = 0; i < 8; ++i) oacc[i] = (f32x4)0.f;
  float m_i[4], l_i[4];
#pragma unroll
  for (int i = 0; i < 4; ++i) { m_i[i] = -INFINITY; l_i[i] = 0.f; }
  const float scale = 0.08838834764831845f;  // 1/sqrt(128)

  // V staging decode: thread covers V row (tid>>2), dh cols [(tid&3)*32, +32)
  const int v_kv = tid >> 2;
  const int v_d0 = (tid & 3) * 32;

  const int nkt = blockIdx.x + 1;
  for (int kt = 0; kt < nkt; ++kt) {
    const int k0 = kt * 64;
    // ---- stage K, XOR-swizzled via pre-swizzled SOURCE (LDS dest linear) ----
#pragma unroll
    for (int it = 0; it < 4; ++it) {
      int ci = it * 256 + tid;                       // 16B chunk index
      int row = ci >> 4;
      int cb = ((ci & 15) * 16) ^ ((row & 7) << 4);  // swizzled byte col in row
      async16(Kb + (size_t)(k0 + row) * DH + (cb >> 1), &Ks[ci * 8]);
    }
    // ---- stage V transposed: Vt[dh][kv], row stride 72 ----
#pragma unroll
    for (int c = 0; c < 4; ++c) {
      short8 vv = *(const short8*)(Vb + (size_t)(k0 + v_kv) * DH + v_d0 + c * 8);
      const ushort* p8 = (const ushort*)&vv;
#pragma unroll
      for (int j = 0; j < 8; ++j)
        Vt[(v_d0 + c * 8 + j) * 72 + v_kv] = p8[j];
    }
    __syncthreads();

    // ---- QK^T : S[16 q][64 keys] per wave ----
    f32x4 sacc[4];
#pragma unroll
    for (int nf = 0; nf < 4; ++nf) sacc[nf] = (f32x4)0.f;
#pragma unroll
    for (int nf = 0; nf < 4; ++nf) {
      int row = nf * 16 + l16;
#pragma unroll
      for (int ks = 0; ks < 4; ++ks) {
        int cb = (ks * 64 + g * 16) ^ ((l16 & 7) << 4);
        short8 kf = *(const short8*)&Ks[row * 128 + (cb >> 1)];
        sacc[nf] = __builtin_amdgcn_mfma_f32_16x16x32_bf16(qf[ks], kf, sacc[nf], 0, 0, 0);
      }
    }

    // ---- online softmax ----
#pragma unroll
    for (int i = 0; i < 4; ++i) {
      int qrow = q0 + w * 16 + g * 4 + i;
      float pv[4];
#pragma unroll
      for (int nf = 0; nf < 4; ++nf) {
        pv[nf] = sacc[nf][i] * scale;
        if (k0 + nf * 16 + l16 > qrow) pv[nf] = -INFINITY;
      }
      float mx = fmaxf(fmaxf(pv[0], pv[1]), fmaxf(pv[2], pv[3]));
#pragma unroll
      for (int d = 1; d < 16; d <<= 1) mx = fmaxf(mx, __shfl_xor(mx, d, 64));
      float mnew = fmaxf(m_i[i], mx);
      float alpha = __expf(m_i[i] - mnew);
      float p[4], sum = 0.f;
#pragma unroll
      for (int nf = 0; nf < 4; ++nf) { p[nf] = __expf(pv[nf] - mnew); sum += p[nf]; }
#pragma unroll
      for (int d = 1; d < 16; d <<= 1) sum += __shfl_xor(sum, d, 64);
      l_i[i] = l_i[i] * alpha + sum;
      m_i[i] = mnew;
#pragma unroll
      for (int nf2 = 0; nf2 < 8; ++nf2) oacc[nf2][i] *= alpha;
#pragma unroll
      for (int nf = 0; nf < 4; ++nf)
        Ps[w * 1152 + (g * 4 + i) * 72 + nf * 16 + l16] = f2bf(p[nf]);
    }
    __asm__ volatile("s_waitcnt lgkmcnt(0)" ::: "memory");
    __builtin_amdgcn_sched_barrier(0);

    // ---- PV: O[16 q][128 dh] += P[16][64] @ V[64][128] ----
#pragma unroll
    for (int kvh = 0; kvh < 2; ++kvh) {
      short8 pa = *(const short8*)&Ps[w * 1152 + l16 * 72 + kvh * 32 + g * 8];
#pragma unroll
      for (int nf2 = 0; nf2 < 8; ++nf2) {
        short8 vf = *(const short8*)&Vt[(nf2 * 16 + l16) * 72 + kvh * 32 + g * 8];
        oacc[nf2] = __builtin_amdgcn_mfma_f32_16x16x32_bf16(pa, vf, oacc[nf2], 0, 0, 0);
      }
    }
    __syncthreads();
  }

#pragma unroll
  for (int i = 0; i < 4; ++i) {
    float inv = 1.f / l_i[i];
    int row = q0 + w * 16 + g * 4 + i;
    size_t obase = ((size_t)b * SEQ + row) * DMODEL + h * DH;
#pragma unroll
    for (int nf2 = 0; nf2 < 8; ++nf2)
      O[obase + nf2 * 16 + l16] = f2bf(oacc[nf2][i] * inv);
  }
}

// ---------------- launch ----------------
extern "C" void kernel_launch(void* const* d_in, const int* in_sizes, int n_in,
                              void* d_out, int out_size, void* d_ws, size_t ws_size,
                              hipStream_t stream) {
  const float* x    = (const float*)d_in[0];
  const float* wqkv = (const float*)d_in[1];
  const float* wout = (const float*)d_in[2];
  const int*   spp  = (const int*)d_in[3];
  float* out = (float*)d_out;

  ushort* ws = (ushort*)d_ws;
  ushort* xb  = ws;                       // 8,388,608
  ushort* wqb = xb + 8388608;             // 12,582,912
  ushort* wob = wqb + 12582912;           // 4,194,304
  ushort* q   = wob + 4194304;            // 8,388,608
  ushort* k   = q + 8388608;
  ushort* v   = k + 8388608;
  ushort* ao  = v + 8388608;              // 8,388,608

  cast_kernel<<<8388608 / 1024, 256, 0, stream>>>(x, xb, 8388608 / 4);
  cast_kernel<<<12582912 / 1024, 256, 0, stream>>>(wqkv, wqb, 12582912 / 4);
  cast_kernel<<<4194304 / 1024, 256, 0, stream>>>(wout, wob, 4194304 / 4);

  gemm_bt<0><<<dim3(6144 / 128, 4096 / 128), 256, 0, stream>>>(xb, wqb, 6144, q, k, v, nullptr);

  rope_kernel<<<4194304 / 256, 256, 0, stream>>>(q, k, spp);

  attn_kernel<<<dim3(SEQ / 64, NH, 2), 256, 0, stream>>>(q, k, v, ao);

  gemm_bt<1><<<dim3(2048 / 128, 4096 / 128), 256, 0, stream>>>(ao, wob, 2048, nullptr, nullptr, nullptr, out);
}

// Round 5
// 359.562 us; speedup vs baseline: 1.6159x; 1.1769x over previous
//
#include <hip/hip_runtime.h>

typedef unsigned short ushort;
typedef __attribute__((ext_vector_type(8))) short short8;
typedef __attribute__((ext_vector_type(4))) float f32x4;

#define NH 16
#define DH 128
#define SEQ 2048
#define DMODEL 2048
#define GK 2048   // K dim for both GEMMs

__device__ __forceinline__ ushort f2bf(float f) {
  union { float f; unsigned u; } v; v.f = f;
  unsigned u = v.u;
  unsigned r = (u + 0x7fffu + ((u >> 16) & 1u)) >> 16;
  return (ushort)r;
}
__device__ __forceinline__ float bf2f(ushort h) {
  union { unsigned u; float f; } v; v.u = ((unsigned)h) << 16; return v.f;
}

__device__ __forceinline__ void async16(const ushort* g, ushort* l) {
  __builtin_amdgcn_global_load_lds(
      (const __attribute__((address_space(1))) unsigned*)g,
      (__attribute__((address_space(3))) unsigned*)l, 16, 0, 0);
}

// ---------------- cast fp32 -> bf16, 4 elems/thread ----------------
__global__ void cast_kernel(const float* __restrict__ src, ushort* __restrict__ dst, int n4) {
  int i = blockIdx.x * blockDim.x + threadIdx.x;
  if (i >= n4) return;
  float4 v = ((const float4*)src)[i];
  unsigned long long p = (unsigned long long)f2bf(v.x)
                       | ((unsigned long long)f2bf(v.y) << 16)
                       | ((unsigned long long)f2bf(v.z) << 32)
                       | ((unsigned long long)f2bf(v.w) << 48);
  ((unsigned long long*)dst)[i] = p;
}

// ---------------- GEMM: C[M,N] = A[M,K] * B[N,K]^T (bf16 MFMA) ----------------
template<int MODE>
__global__ __launch_bounds__(256, 2)
void gemm_bt(const ushort* __restrict__ A, const ushort* __restrict__ B, int N,
             ushort* __restrict__ oq, ushort* __restrict__ ok, ushort* __restrict__ ov,
             float* __restrict__ of) {
  __shared__ ushort As[128 * 64];
  __shared__ ushort Bs[128 * 64];
  const int tid = threadIdx.x;
  const int lane = tid & 63;
  const int w = tid >> 6;
  const int wr = w >> 1, wc = w & 1;
  const int g = lane >> 4, l16 = lane & 15;
  const int m0 = blockIdx.y * 128;
  const int n0 = blockIdx.x * 128;

  f32x4 acc[4][4];
#pragma unroll
  for (int i = 0; i < 4; ++i)
#pragma unroll
    for (int j = 0; j < 4; ++j) acc[i][j] = (f32x4)0.f;

  const ushort* Ablk = A + (size_t)m0 * GK;
  const ushort* Bblk = B + (size_t)n0 * GK;

  for (int k0 = 0; k0 < GK; k0 += 64) {
#pragma unroll
    for (int it = 0; it < 4; ++it) {
      int e = (it * 256 + tid) * 8;          // element idx in 128x64 tile
      int row = e >> 6, col = e & 63;
      async16(Ablk + (size_t)row * GK + k0 + col, &As[e]);
      async16(Bblk + (size_t)row * GK + k0 + col, &Bs[e]);
    }
    __syncthreads();
#pragma unroll
    for (int ks = 0; ks < 2; ++ks) {
      short8 af[4], bf[4];
#pragma unroll
      for (int mf = 0; mf < 4; ++mf)
        af[mf] = *(const short8*)&As[(wr * 64 + mf * 16 + l16) * 64 + ks * 32 + g * 8];
#pragma unroll
      for (int nf = 0; nf < 4; ++nf)
        bf[nf] = *(const short8*)&Bs[(wc * 64 + nf * 16 + l16) * 64 + ks * 32 + g * 8];
#pragma unroll
      for (int mf = 0; mf < 4; ++mf)
#pragma unroll
        for (int nf = 0; nf < 4; ++nf)
          acc[mf][nf] = __builtin_amdgcn_mfma_f32_16x16x32_bf16(af[mf], bf[nf], acc[mf][nf], 0, 0, 0);
    }
    __syncthreads();
  }

#pragma unroll
  for (int mf = 0; mf < 4; ++mf)
#pragma unroll
    for (int nf = 0; nf < 4; ++nf)
#pragma unroll
      for (int i = 0; i < 4; ++i) {
        int row = m0 + wr * 64 + mf * 16 + g * 4 + i;
        int col = n0 + wc * 64 + nf * 16 + l16;
        float val = acc[mf][nf][i];
        if (MODE == 0) {
          int which = col >> 11;
          int r = col & 2047;
          int h = r >> 7, dh = r & 127;
          int b = row >> 11, s = row & 2047;
          size_t dst = ((size_t)(b * NH + h) * SEQ + s) * DH + dh;
          ushort* o = (which == 0) ? oq : (which == 1 ? ok : ov);
          o[dst] = f2bf(val);
        } else {
          of[(size_t)row * N + col] = val;
        }
      }
}

// ---------------- RoPE (in-place on head-major bf16 q,k) ----------------
__global__ void rope_kernel(ushort* __restrict__ q, ushort* __restrict__ k,
                            const int* __restrict__ spp) {
  int id = blockIdx.x * blockDim.x + threadIdx.x;   // < B*H*S*64
  int j = id & 63;
  int s = (id >> 6) & (SEQ - 1);
  int bh = id >> 17;
  size_t base = ((size_t)bh * SEQ + s) * DH;
  float pos = (float)(s + spp[0]);
  float ang = pos * __expf(-(float)j * (9.210340371976184f / 64.f)); // 1/10000^(j/64)
  float c = cosf(ang), sn = sinf(ang);
  float q1 = bf2f(q[base + j]), q2 = bf2f(q[base + 64 + j]);
  q[base + j]      = f2bf(q1 * c - q2 * sn);
  q[base + 64 + j] = f2bf(q2 * c + q1 * sn);
  float k1 = bf2f(k[base + j]), k2 = bf2f(k[base + 64 + j]);
  k[base + j]      = f2bf(k1 * c - k2 * sn);
  k[base + 64 + j] = f2bf(k2 * c + k1 * sn);
}

// ---------------- causal flash attention ----------------
// grid: (S/128, H, B) with REVERSED q-tile order (long blocks launch first).
// 256 threads = 4 waves; wave w owns 32 q rows (2 row-groups of 16).
// KBLK=64, double-buffered K (XOR-swizzled via pre-swizzled source) and
// Vt (transposed, stride 72, XOR kv-swizzle, ushort2 conflict-free writes).
// One barrier per tile: stage(t+1) issued before compute(t) (T3/T14 pattern).
__global__ __launch_bounds__(256, 2)
void attn_kernel(const ushort* __restrict__ Q, const ushort* __restrict__ K,
                 const ushort* __restrict__ V, ushort* __restrict__ O) {
  __shared__ ushort Ks[2][64 * 128];     // 32 KB
  __shared__ ushort Vt[2][128 * 72];     // 36 KB
  __shared__ ushort Ps[4][16 * 72];      // 9 KB
  const int tid = threadIdx.x;
  const int lane = tid & 63;
  const int w = tid >> 6;
  const int g = lane >> 4, l16 = lane & 15;
  const int qt = (int)(gridDim.x - 1) - (int)blockIdx.x;   // long blocks first
  const int q0 = qt * 128;
  const int h = blockIdx.y, b = blockIdx.z;
  const int bh = b * NH + h;
  const ushort* Qb = Q + (size_t)bh * SEQ * DH;
  const ushort* Kb = K + (size_t)bh * SEQ * DH;
  const ushort* Vb = V + (size_t)bh * SEQ * DH;

  short8 qf[2][4];
#pragma unroll
  for (int rg = 0; rg < 2; ++rg) {
    const ushort* qrow = Qb + (size_t)(q0 + w * 32 + rg * 16 + l16) * DH;
#pragma unroll
    for (int ks = 0; ks < 4; ++ks) qf[rg][ks] = *(const short8*)(qrow + ks * 32 + g * 8);
  }
  f32x4 oacc[2][8];
#pragma unroll
  for (int rg = 0; rg < 2; ++rg)
#pragma unroll
    for (int i = 0; i < 8; ++i) oacc[rg][i] = (f32x4)0.f;
  float m_i[2][4], l_i[2][4];
#pragma unroll
  for (int rg = 0; rg < 2; ++rg)
#pragma unroll
    for (int i = 0; i < 4; ++i) { m_i[rg][i] = -INFINITY; l_i[rg][i] = 0.f; }
  const float scale = 0.08838834764831845f;  // 1/sqrt(128)

  // V staging decode: thread covers kv rows {vkv, vkv+1} x cols [vd0, vd0+16)
  const int vkv = (tid >> 3) * 2;       // 0..62
  const int vd0 = (tid & 7) * 16;       // 0..112
  const int vmask = (tid & 7) << 3;     // XOR swizzle for writes ((d>>4)&7)<<3

  const int nkt = 2 * qt + 2;

  // ---- prologue: stage tile 0 into buffer 0 ----
#pragma unroll
  for (int it = 0; it < 4; ++it) {
    int ci = it * 256 + tid;
    int row = ci >> 4;
    int cb = ((ci & 15) * 16) ^ ((row & 7) << 4);
    async16(Kb + (size_t)row * DH + (cb >> 1), &Ks[0][ci * 8]);
  }
  {
    short8 vr[4];
    vr[0] = *(const short8*)(Vb + (size_t)vkv * DH + vd0);
    vr[1] = *(const short8*)(Vb + (size_t)vkv * DH + vd0 + 8);
    vr[2] = *(const short8*)(Vb + (size_t)(vkv + 1) * DH + vd0);
    vr[3] = *(const short8*)(Vb + (size_t)(vkv + 1) * DH + vd0 + 8);
#pragma unroll
    for (int j = 0; j < 16; ++j) {
      int d = vd0 + j;
      const ushort* a = (const ushort*)&vr[j >> 3];
      const ushort* c = (const ushort*)&vr[2 + (j >> 3)];
      unsigned val = (unsigned)a[j & 7] | ((unsigned)c[j & 7] << 16);
      *(unsigned*)&Vt[0][d * 72 + (vkv ^ vmask)] = val;
    }
  }
  __syncthreads();

  int cur = 0;
  for (int t = 0; t < nkt; ++t) {
    const int k0 = t * 64;
    const int nxt = cur ^ 1;
    const bool pre = (t + 1 < nkt);
    short8 vr[4];
    if (pre) {
      const int kn = (t + 1) * 64;
#pragma unroll
      for (int it = 0; it < 4; ++it) {
        int ci = it * 256 + tid;
        int row = ci >> 4;
        int cb = ((ci & 15) * 16) ^ ((row & 7) << 4);
        async16(Kb + (size_t)(kn + row) * DH + (cb >> 1), &Ks[nxt][ci * 8]);
      }
      vr[0] = *(const short8*)(Vb + (size_t)(kn + vkv) * DH + vd0);
      vr[1] = *(const short8*)(Vb + (size_t)(kn + vkv) * DH + vd0 + 8);
      vr[2] = *(const short8*)(Vb + (size_t)(kn + vkv + 1) * DH + vd0);
      vr[3] = *(const short8*)(Vb + (size_t)(kn + vkv + 1) * DH + vd0 + 8);
    }

    // ---- compute tile t from buffer cur ----
#pragma unroll
    for (int rg = 0; rg < 2; ++rg) {
      const int rbase = q0 + w * 32 + rg * 16;
      if (k0 <= rbase + 15) {
        // QK^T : S[16 q][64 keys]
        f32x4 sacc[4];
#pragma unroll
        for (int nf = 0; nf < 4; ++nf) sacc[nf] = (f32x4)0.f;
#pragma unroll
        for (int nf = 0; nf < 4; ++nf) {
          int row = nf * 16 + l16;
#pragma unroll
          for (int ks = 0; ks < 4; ++ks) {
            int cb = (ks * 64 + g * 16) ^ ((l16 & 7) << 4);
            short8 kf = *(const short8*)&Ks[cur][row * 128 + (cb >> 1)];
            sacc[nf] = __builtin_amdgcn_mfma_f32_16x16x32_bf16(qf[rg][ks], kf, sacc[nf], 0, 0, 0);
          }
        }
        // online softmax
#pragma unroll
        for (int i = 0; i < 4; ++i) {
          int qrow = rbase + g * 4 + i;
          float pv[4];
#pragma unroll
          for (int nf = 0; nf < 4; ++nf) {
            pv[nf] = sacc[nf][i] * scale;
            if (k0 + nf * 16 + l16 > qrow) pv[nf] = -INFINITY;
          }
          float mx = fmaxf(fmaxf(pv[0], pv[1]), fmaxf(pv[2], pv[3]));
#pragma unroll
          for (int d = 1; d < 16; d <<= 1) mx = fmaxf(mx, __shfl_xor(mx, d, 64));
          float mnew = fmaxf(m_i[rg][i], mx);
          float alpha = __expf(m_i[rg][i] - mnew);
          float p[4], sum = 0.f;
#pragma unroll
          for (int nf = 0; nf < 4; ++nf) { p[nf] = __expf(pv[nf] - mnew); sum += p[nf]; }
#pragma unroll
          for (int d = 1; d < 16; d <<= 1) sum += __shfl_xor(sum, d, 64);
          l_i[rg][i] = l_i[rg][i] * alpha + sum;
          m_i[rg][i] = mnew;
#pragma unroll
          for (int nf2 = 0; nf2 < 8; ++nf2) oacc[rg][nf2][i] *= alpha;
#pragma unroll
          for (int nf = 0; nf < 4; ++nf)
            Ps[w][(g * 4 + i) * 72 + nf * 16 + l16] = f2bf(p[nf]);
        }
        __asm__ volatile("s_waitcnt lgkmcnt(0)" ::: "memory");
        __builtin_amdgcn_sched_barrier(0);

        // PV: O[16 q][128 dh] += P[16][64] @ V[64][128]
#pragma unroll
        for (int kvh = 0; kvh < 2; ++kvh) {
          short8 pa = *(const short8*)&Ps[w][l16 * 72 + kvh * 32 + g * 8];
#pragma unroll
          for (int nf2 = 0; nf2 < 8; ++nf2) {
            int cb = (kvh * 32 + g * 8) ^ (nf2 * 8);
            short8 vf = *(const short8*)&Vt[cur][(nf2 * 16 + l16) * 72 + cb];
            oacc[rg][nf2] = __builtin_amdgcn_mfma_f32_16x16x32_bf16(pa, vf, oacc[rg][nf2], 0, 0, 0);
          }
        }
      }
    }

    if (pre) {
#pragma unroll
      for (int j = 0; j < 16; ++j) {
        int d = vd0 + j;
        const ushort* a = (const ushort*)&vr[j >> 3];
        const ushort* c = (const ushort*)&vr[2 + (j >> 3)];
        unsigned val = (unsigned)a[j & 7] | ((unsigned)c[j & 7] << 16);
        *(unsigned*)&Vt[nxt][d * 72 + (vkv ^ vmask)] = val;
      }
    }
    __syncthreads();
    cur = nxt;
  }

#pragma unroll
  for (int rg = 0; rg < 2; ++rg)
#pragma unroll
    for (int i = 0; i < 4; ++i) {
      float inv = 1.f / l_i[rg][i];
      int row = q0 + w * 32 + rg * 16 + g * 4 + i;
      size_t obase = ((size_t)b * SEQ + row) * DMODEL + h * DH;
#pragma unroll
      for (int nf2 = 0; nf2 < 8; ++nf2)
        O[obase + nf2 * 16 + l16] = f2bf(oacc[rg][nf2][i] * inv);
    }
}

// ---------------- launch ----------------
extern "C" void kernel_launch(void* const* d_in, const int* in_sizes, int n_in,
                              void* d_out, int out_size, void* d_ws, size_t ws_size,
                              hipStream_t stream) {
  const float* x    = (const float*)d_in[0];
  const float* wqkv = (const float*)d_in[1];
  const float* wout = (const float*)d_in[2];
  const int*   spp  = (const int*)d_in[3];
  float* out = (float*)d_out;

  ushort* ws = (ushort*)d_ws;
  ushort* xb  = ws;                       // 8,388,608
  ushort* wqb = xb + 8388608;             // 12,582,912
  ushort* wob = wqb + 12582912;           // 4,194,304
  ushort* q   = wob + 4194304;            // 8,388,608
  ushort* k   = q + 8388608;
  ushort* v   = k + 8388608;
  ushort* ao  = v + 8388608;              // 8,388,608

  cast_kernel<<<8388608 / 1024, 256, 0, stream>>>(x, xb, 8388608 / 4);
  cast_kernel<<<12582912 / 1024, 256, 0, stream>>>(wqkv, wqb, 12582912 / 4);
  cast_kernel<<<4194304 / 1024, 256, 0, stream>>>(wout, wob, 4194304 / 4);

  gemm_bt<0><<<dim3(6144 / 128, 4096 / 128), 256, 0, stream>>>(xb, wqb, 6144, q, k, v, nullptr);

  rope_kernel<<<4194304 / 256, 256, 0, stream>>>(q, k, spp);

  attn_kernel<<<dim3(SEQ / 128, NH, 2), 256, 0, stream>>>(q, k, v, ao);

  gemm_bt<1><<<dim3(2048 / 128, 4096 / 128), 256, 0, stream>>>(ao, wob, 2048, nullptr, nullptr, nullptr, out);
}

// Round 6
// 300.142 us; speedup vs baseline: 1.9358x; 1.1980x over previous
//
#include <hip/hip_runtime.h>

typedef unsigned short ushort;
typedef __attribute__((ext_vector_type(8))) short short8;
typedef __attribute__((ext_vector_type(4))) float f32x4;

#define NH 16
#define DH 128
#define SEQ 2048
#define DMODEL 2048
#define GK 2048   // K dim for both GEMMs

__device__ __forceinline__ ushort f2bf(float f) {
  union { float f; unsigned u; } v; v.f = f;
  unsigned u = v.u;
  unsigned r = (u + 0x7fffu + ((u >> 16) & 1u)) >> 16;
  return (ushort)r;
}
__device__ __forceinline__ float bf2f(ushort h) {
  union { unsigned u; float f; } v; v.u = ((unsigned)h) << 16; return v.f;
}

__device__ __forceinline__ void async16(const ushort* g, ushort* l) {
  __builtin_amdgcn_global_load_lds(
      (const __attribute__((address_space(1))) unsigned*)g,
      (__attribute__((address_space(3))) unsigned*)l, 16, 0, 0);
}

// ---------------- cast fp32 -> bf16, 4 elems/thread ----------------
__global__ void cast_kernel(const float* __restrict__ src, ushort* __restrict__ dst, int n4) {
  int i = blockIdx.x * blockDim.x + threadIdx.x;
  if (i >= n4) return;
  float4 v = ((const float4*)src)[i];
  unsigned long long p = (unsigned long long)f2bf(v.x)
                       | ((unsigned long long)f2bf(v.y) << 16)
                       | ((unsigned long long)f2bf(v.z) << 32)
                       | ((unsigned long long)f2bf(v.w) << 48);
  ((unsigned long long*)dst)[i] = p;
}

// ---------------- GEMM: C[M,N] = A[M,K] * B[N,K]^T (bf16 MFMA) ----------------
template<int MODE>
__global__ __launch_bounds__(256, 2)
void gemm_bt(const ushort* __restrict__ A, const ushort* __restrict__ B, int N,
             ushort* __restrict__ oq, ushort* __restrict__ ok, ushort* __restrict__ ov,
             float* __restrict__ of) {
  __shared__ ushort As[128 * 64];
  __shared__ ushort Bs[128 * 64];
  const int tid = threadIdx.x;
  const int lane = tid & 63;
  const int w = tid >> 6;
  const int wr = w >> 1, wc = w & 1;
  const int g = lane >> 4, l16 = lane & 15;
  const int m0 = blockIdx.y * 128;
  const int n0 = blockIdx.x * 128;

  f32x4 acc[4][4];
#pragma unroll
  for (int i = 0; i < 4; ++i)
#pragma unroll
    for (int j = 0; j < 4; ++j) acc[i][j] = (f32x4)0.f;

  const ushort* Ablk = A + (size_t)m0 * GK;
  const ushort* Bblk = B + (size_t)n0 * GK;

  for (int k0 = 0; k0 < GK; k0 += 64) {
#pragma unroll
    for (int it = 0; it < 4; ++it) {
      int e = (it * 256 + tid) * 8;          // element idx in 128x64 tile
      int row = e >> 6, col = e & 63;
      async16(Ablk + (size_t)row * GK + k0 + col, &As[e]);
      async16(Bblk + (size_t)row * GK + k0 + col, &Bs[e]);
    }
    __syncthreads();
#pragma unroll
    for (int ks = 0; ks < 2; ++ks) {
      short8 af[4], bf[4];
#pragma unroll
      for (int mf = 0; mf < 4; ++mf)
        af[mf] = *(const short8*)&As[(wr * 64 + mf * 16 + l16) * 64 + ks * 32 + g * 8];
#pragma unroll
      for (int nf = 0; nf < 4; ++nf)
        bf[nf] = *(const short8*)&Bs[(wc * 64 + nf * 16 + l16) * 64 + ks * 32 + g * 8];
#pragma unroll
      for (int mf = 0; mf < 4; ++mf)
#pragma unroll
        for (int nf = 0; nf < 4; ++nf)
          acc[mf][nf] = __builtin_amdgcn_mfma_f32_16x16x32_bf16(af[mf], bf[nf], acc[mf][nf], 0, 0, 0);
    }
    __syncthreads();
  }

#pragma unroll
  for (int mf = 0; mf < 4; ++mf)
#pragma unroll
    for (int nf = 0; nf < 4; ++nf)
#pragma unroll
      for (int i = 0; i < 4; ++i) {
        int row = m0 + wr * 64 + mf * 16 + g * 4 + i;
        int col = n0 + wc * 64 + nf * 16 + l16;
        float val = acc[mf][nf][i];
        if (MODE == 0) {
          int which = col >> 11;
          int r = col & 2047;
          int h = r >> 7, dh = r & 127;
          int b = row >> 11, s = row & 2047;
          size_t dst = ((size_t)(b * NH + h) * SEQ + s) * DH + dh;
          ushort* o = (which == 0) ? oq : (which == 1 ? ok : ov);
          o[dst] = f2bf(val);
        } else {
          of[(size_t)row * N + col] = val;
        }
      }
}

// ---------------- RoPE (in-place on head-major bf16 q,k) ----------------
__global__ void rope_kernel(ushort* __restrict__ q, ushort* __restrict__ k,
                            const int* __restrict__ spp) {
  int id = blockIdx.x * blockDim.x + threadIdx.x;   // < B*H*S*64
  int j = id & 63;
  int s = (id >> 6) & (SEQ - 1);
  int bh = id >> 17;
  size_t base = ((size_t)bh * SEQ + s) * DH;
  float pos = (float)(s + spp[0]);
  float ang = pos * __expf(-(float)j * (9.210340371976184f / 64.f)); // 1/10000^(j/64)
  float c = cosf(ang), sn = sinf(ang);
  float q1 = bf2f(q[base + j]), q2 = bf2f(q[base + 64 + j]);
  q[base + j]      = f2bf(q1 * c - q2 * sn);
  q[base + 64 + j] = f2bf(q2 * c + q1 * sn);
  float k1 = bf2f(k[base + j]), k2 = bf2f(k[base + 64 + j]);
  k[base + j]      = f2bf(k1 * c - k2 * sn);
  k[base + 64 + j] = f2bf(k2 * c + k1 * sn);
}

// ---------------- causal flash attention ----------------
// grid: (16, H, B) = 512 blocks; block bx processes q-tile (31-bx) then q-tile
// bx SEQUENTIALLY -> every block does exactly 33 KV-tiles (uniform load).
// 256 threads = 4 waves; wave w owns 16 q-rows. QBLK=64, KBLK=64.
// Double-buffered K (XOR-swizzled, pre-swizzled source) and Vt (transposed,
// stride 72, XOR kv-swizzle). One barrier per tile (stage t+1 before compute t).
__global__ __launch_bounds__(256, 2)
void attn_kernel(const ushort* __restrict__ Q, const ushort* __restrict__ K,
                 const ushort* __restrict__ V, ushort* __restrict__ O) {
  __shared__ ushort Ks[2][64 * 128];     // 32 KB
  __shared__ ushort Vt[2][128 * 72];     // 36 KB
  __shared__ ushort Ps[4][16 * 72];      // 9 KB
  const int tid = threadIdx.x;
  const int lane = tid & 63;
  const int w = tid >> 6;
  const int g = lane >> 4, l16 = lane & 15;
  const int h = blockIdx.y, b = blockIdx.z;
  const int bh = b * NH + h;
  const ushort* Qb = Q + (size_t)bh * SEQ * DH;
  const ushort* Kb = K + (size_t)bh * SEQ * DH;
  const ushort* Vb = V + (size_t)bh * SEQ * DH;
  const float scale = 0.08838834764831845f;  // 1/sqrt(128)

  // V staging decode: thread covers kv rows {vkv, vkv+1} x cols [vd0, vd0+16)
  const int vkv = (tid >> 3) * 2;       // 0..62
  const int vd0 = (tid & 7) * 16;       // 0..112
  const int vmask = (tid & 7) << 3;     // XOR swizzle ((d>>4)&7)<<3

  for (int pass = 0; pass < 2; ++pass) {
    const int qt = pass == 0 ? (31 - (int)blockIdx.x) : (int)blockIdx.x;
    const int q0 = qt * 64;
    const int nkt = qt + 1;

    short8 qf[4];
    {
      const ushort* qrow = Qb + (size_t)(q0 + w * 16 + l16) * DH;
#pragma unroll
      for (int ks = 0; ks < 4; ++ks) qf[ks] = *(const short8*)(qrow + ks * 32 + g * 8);
    }
    f32x4 oacc[8];
#pragma unroll
    for (int i = 0; i < 8; ++i) oacc[i] = (f32x4)0.f;
    float m_i[4], l_i[4];
#pragma unroll
    for (int i = 0; i < 4; ++i) { m_i[i] = -INFINITY; l_i[i] = 0.f; }

    // ---- prologue: stage tile 0 into buffer 0 ----
#pragma unroll
    for (int it = 0; it < 4; ++it) {
      int ci = it * 256 + tid;
      int row = ci >> 4;
      int cb = ((ci & 15) * 16) ^ ((row & 7) << 4);
      async16(Kb + (size_t)row * DH + (cb >> 1), &Ks[0][ci * 8]);
    }
    {
      short8 vr[4];
      vr[0] = *(const short8*)(Vb + (size_t)vkv * DH + vd0);
      vr[1] = *(const short8*)(Vb + (size_t)vkv * DH + vd0 + 8);
      vr[2] = *(const short8*)(Vb + (size_t)(vkv + 1) * DH + vd0);
      vr[3] = *(const short8*)(Vb + (size_t)(vkv + 1) * DH + vd0 + 8);
#pragma unroll
      for (int j = 0; j < 16; ++j) {
        int d = vd0 + j;
        const ushort* a = (const ushort*)&vr[j >> 3];
        const ushort* c = (const ushort*)&vr[2 + (j >> 3)];
        unsigned val = (unsigned)a[j & 7] | ((unsigned)c[j & 7] << 16);
        *(unsigned*)&Vt[0][d * 72 + (vkv ^ vmask)] = val;
      }
    }
    __syncthreads();

    int cur = 0;
    for (int t = 0; t < nkt; ++t) {
      const int k0 = t * 64;
      const int nxt = cur ^ 1;
      const bool pre = (t + 1 < nkt);
      short8 vr[4];
      if (pre) {
        const int kn = (t + 1) * 64;
#pragma unroll
        for (int it = 0; it < 4; ++it) {
          int ci = it * 256 + tid;
          int row = ci >> 4;
          int cb = ((ci & 15) * 16) ^ ((row & 7) << 4);
          async16(Kb + (size_t)(kn + row) * DH + (cb >> 1), &Ks[nxt][ci * 8]);
        }
        vr[0] = *(const short8*)(Vb + (size_t)(kn + vkv) * DH + vd0);
        vr[1] = *(const short8*)(Vb + (size_t)(kn + vkv) * DH + vd0 + 8);
        vr[2] = *(const short8*)(Vb + (size_t)(kn + vkv + 1) * DH + vd0);
        vr[3] = *(const short8*)(Vb + (size_t)(kn + vkv + 1) * DH + vd0 + 8);
      }

      // ---- QK^T : S[16 q][64 keys] per wave ----
      f32x4 sacc[4];
#pragma unroll
      for (int nf = 0; nf < 4; ++nf) sacc[nf] = (f32x4)0.f;
      __builtin_amdgcn_s_setprio(1);
#pragma unroll
      for (int nf = 0; nf < 4; ++nf) {
        int row = nf * 16 + l16;
#pragma unroll
        for (int ks = 0; ks < 4; ++ks) {
          int cb = (ks * 64 + g * 16) ^ ((l16 & 7) << 4);
          short8 kf = *(const short8*)&Ks[cur][row * 128 + (cb >> 1)];
          sacc[nf] = __builtin_amdgcn_mfma_f32_16x16x32_bf16(qf[ks], kf, sacc[nf], 0, 0, 0);
        }
      }
      __builtin_amdgcn_s_setprio(0);

      // ---- online softmax ----
#pragma unroll
      for (int i = 0; i < 4; ++i) {
        int qrow = q0 + w * 16 + g * 4 + i;
        float pv[4];
#pragma unroll
        for (int nf = 0; nf < 4; ++nf) {
          pv[nf] = sacc[nf][i] * scale;
          if (k0 + nf * 16 + l16 > qrow) pv[nf] = -INFINITY;
        }
        float mx = fmaxf(fmaxf(pv[0], pv[1]), fmaxf(pv[2], pv[3]));
#pragma unroll
        for (int d = 1; d < 16; d <<= 1) mx = fmaxf(mx, __shfl_xor(mx, d, 64));
        float mnew = fmaxf(m_i[i], mx);
        float alpha = __expf(m_i[i] - mnew);
        float p[4], sum = 0.f;
#pragma unroll
        for (int nf = 0; nf < 4; ++nf) { p[nf] = __expf(pv[nf] - mnew); sum += p[nf]; }
#pragma unroll
        for (int d = 1; d < 16; d <<= 1) sum += __shfl_xor(sum, d, 64);
        l_i[i] = l_i[i] * alpha + sum;
        m_i[i] = mnew;
#pragma unroll
        for (int nf2 = 0; nf2 < 8; ++nf2) oacc[nf2][i] *= alpha;
#pragma unroll
        for (int nf = 0; nf < 4; ++nf)
          Ps[w][(g * 4 + i) * 72 + nf * 16 + l16] = f2bf(p[nf]);
      }
      __asm__ volatile("s_waitcnt lgkmcnt(0)" ::: "memory");
      __builtin_amdgcn_sched_barrier(0);

      // ---- PV: O[16 q][128 dh] += P[16][64] @ V[64][128] ----
      __builtin_amdgcn_s_setprio(1);
#pragma unroll
      for (int kvh = 0; kvh < 2; ++kvh) {
        short8 pa = *(const short8*)&Ps[w][l16 * 72 + kvh * 32 + g * 8];
#pragma unroll
        for (int nf2 = 0; nf2 < 8; ++nf2) {
          int cb = (kvh * 32 + g * 8) ^ (nf2 * 8);
          short8 vf = *(const short8*)&Vt[cur][(nf2 * 16 + l16) * 72 + cb];
          oacc[nf2] = __builtin_amdgcn_mfma_f32_16x16x32_bf16(pa, vf, oacc[nf2], 0, 0, 0);
        }
      }
      __builtin_amdgcn_s_setprio(0);

      if (pre) {
#pragma unroll
        for (int j = 0; j < 16; ++j) {
          int d = vd0 + j;
          const ushort* a = (const ushort*)&vr[j >> 3];
          const ushort* c = (const ushort*)&vr[2 + (j >> 3)];
          unsigned val = (unsigned)a[j & 7] | ((unsigned)c[j & 7] << 16);
          *(unsigned*)&Vt[nxt][d * 72 + (vkv ^ vmask)] = val;
        }
      }
      __syncthreads();
      cur = nxt;
    }

    // ---- epilogue: write O rows for this pass ----
#pragma unroll
    for (int i = 0; i < 4; ++i) {
      float inv = 1.f / l_i[i];
      int row = q0 + w * 16 + g * 4 + i;
      size_t obase = ((size_t)b * SEQ + row) * DMODEL + h * DH;
#pragma unroll
      for (int nf2 = 0; nf2 < 8; ++nf2)
        O[obase + nf2 * 16 + l16] = f2bf(oacc[nf2][i] * inv);
    }
  }
}

// ---------------- launch ----------------
extern "C" void kernel_launch(void* const* d_in, const int* in_sizes, int n_in,
                              void* d_out, int out_size, void* d_ws, size_t ws_size,
                              hipStream_t stream) {
  const float* x    = (const float*)d_in[0];
  const float* wqkv = (const float*)d_in[1];
  const float* wout = (const float*)d_in[2];
  const int*   spp  = (const int*)d_in[3];
  float* out = (float*)d_out;

  ushort* ws = (ushort*)d_ws;
  ushort* xb  = ws;                       // 8,388,608
  ushort* wqb = xb + 8388608;             // 12,582,912
  ushort* wob = wqb + 12582912;           // 4,194,304
  ushort* q   = wob + 4194304;            // 8,388,608
  ushort* k   = q + 8388608;
  ushort* v   = k + 8388608;
  ushort* ao  = v + 8388608;              // 8,388,608

  cast_kernel<<<8388608 / 1024, 256, 0, stream>>>(x, xb, 8388608 / 4);
  cast_kernel<<<12582912 / 1024, 256, 0, stream>>>(wqkv, wqb, 12582912 / 4);
  cast_kernel<<<4194304 / 1024, 256, 0, stream>>>(wout, wob, 4194304 / 4);

  gemm_bt<0><<<dim3(6144 / 128, 4096 / 128), 256, 0, stream>>>(xb, wqb, 6144, q, k, v, nullptr);

  rope_kernel<<<4194304 / 256, 256, 0, stream>>>(q, k, spp);

  attn_kernel<<<dim3(16, NH, 2), 256, 0, stream>>>(q, k, v, ao);

  gemm_bt<1><<<dim3(2048 / 128, 4096 / 128), 256, 0, stream>>>(ao, wob, 2048, nullptr, nullptr, nullptr, out);
}